// Round 2
// baseline (928.707 us; speedup 1.0000x reference)
//
#include <hip/hip_runtime.h>
#include <stdint.h>

// Problem constants
#define QP 127.0f
#define HW2 50176            // 224*224
#define NPIX 1605632         // 32*224*224
#define NELEM 25690112       // 32*16*224*224

// ws layout (bytes)
#define WS_WQ   256          // 576 dwords packed weights
#define WS_PART 4096         // 1568*32 floats of per-block stat partials
#define WS_XQ   (1 << 20)    // NPIX * 16B of cin-packed int8 activations

__device__ __forceinline__ int dot4(int a, int b, int c) {
#if defined(__has_builtin) && __has_builtin(__builtin_amdgcn_sdot4)
  return __builtin_amdgcn_sdot4(a, b, c, false);
#else
  int r = c;
  r += (int)(signed char)(a)       * (int)(signed char)(b);
  r += (int)(signed char)(a >> 8)  * (int)(signed char)(b >> 8);
  r += (int)(signed char)(a >> 16) * (int)(signed char)(b >> 16);
  r += (a >> 24) * (b >> 24);
  return r;
#endif
}

// ---------------- K1: absmax(x) ----------------
__global__ void k_absmax(const float* __restrict__ x, unsigned* __restrict__ absmax_bits) {
  const float4* x4 = (const float4*)x;
  const int n4 = NELEM / 4;
  float m = 0.0f;
  for (int i = blockIdx.x * blockDim.x + threadIdx.x; i < n4; i += gridDim.x * blockDim.x) {
    float4 v = x4[i];
    m = fmaxf(m, fmaxf(fmaxf(fabsf(v.x), fabsf(v.y)), fmaxf(fabsf(v.z), fabsf(v.w))));
  }
  #pragma unroll
  for (int off = 32; off; off >>= 1) m = fmaxf(m, __shfl_down(m, off, 64));
  __shared__ float red[4];
  int lane = threadIdx.x & 63, wv = threadIdx.x >> 6;
  if (lane == 0) red[wv] = m;
  __syncthreads();
  if (threadIdx.x == 0) {
    m = fmaxf(fmaxf(red[0], red[1]), fmaxf(red[2], red[3]));
    atomicMax(absmax_bits, __float_as_uint(m));  // all values >= 0: uint order == float order
  }
}

// ---------------- K2: quantize weights, compute scales ----------------
__global__ void k_quant_w(const float* __restrict__ w, char* __restrict__ ws) {
  unsigned* hdr_u = (unsigned*)ws;
  float* hdr_f = (float*)ws;
  int* wq = (int*)(ws + WS_WQ);
  float m = 0.0f;
  for (int i = threadIdx.x; i < 2304; i += 256) m = fmaxf(m, fabsf(w[i]));
  #pragma unroll
  for (int off = 32; off; off >>= 1) m = fmaxf(m, __shfl_down(m, off, 64));
  __shared__ float red[4];
  __shared__ float s_sw;
  if ((threadIdx.x & 63) == 0) red[threadIdx.x >> 6] = m;
  __syncthreads();
  if (threadIdx.x == 0) {
    float mw = fmaxf(fmaxf(red[0], red[1]), fmaxf(red[2], red[3]));
    float sw = mw / QP;                              // matches ref: step = alpha/qp (f32 div)
    float sx = __uint_as_float(hdr_u[0]) / QP;
    hdr_f[1] = sw;
    hdr_f[2] = sx * sw;                              // combined dequant scale
    s_sw = sw;
  }
  __syncthreads();
  float sw = s_sw;
  // pack: wq[(cout*9 + kh*3+kw)*4 + c4], byte j of dword = cin 4*c4+j
  for (int i = threadIdx.x; i < 576; i += 256) {
    int cout = i / 36; int r = i - cout * 36;
    int tap = r >> 2;  int c4 = r & 3;
    int kh = tap / 3, kw = tap - kh * 3;
    unsigned bits = 0;
    #pragma unroll
    for (int j = 0; j < 4; ++j) {
      int cin = c4 * 4 + j;
      float v = w[((cout * 16 + cin) * 3 + kh) * 3 + kw];
      int q = (int)rintf(v / sw);                    // rint = round-half-even = jnp.round
      q = max(-127, min(127, q));
      bits |= ((unsigned)(q & 0xff)) << (8 * j);
    }
    wq[i] = (int)bits;
  }
}

// ---------------- K3: quantize x -> NHWC cin-packed int8 ----------------
__global__ void k_quant_x(const float* __restrict__ x, char* __restrict__ ws) {
  const unsigned* hdr_u = (const unsigned*)ws;
  int4* xq = (int4*)(ws + WS_XQ);
  float sx = __uint_as_float(hdr_u[0]) / QP;
  int p = blockIdx.x * 256 + threadIdx.x;            // 6272*256 == NPIX exactly
  int n = p / HW2;
  int hw = p - n * HW2;
  const float* xb = x + (size_t)n * 16 * HW2 + hw;   // coalesced per-channel reads
  int q[16];
  #pragma unroll
  for (int c = 0; c < 16; ++c) {
    float t = xb[c * HW2] / sx;                      // f32 div, matches ref
    int qq = (int)rintf(t);
    q[c] = max(-127, min(127, qq));
  }
  int4 v;
  v.x = (int)(((unsigned)(q[0] & 0xff)) | ((unsigned)(q[1] & 0xff) << 8) | ((unsigned)(q[2] & 0xff) << 16) | ((unsigned)(q[3] & 0xff) << 24));
  v.y = (int)(((unsigned)(q[4] & 0xff)) | ((unsigned)(q[5] & 0xff) << 8) | ((unsigned)(q[6] & 0xff) << 16) | ((unsigned)(q[7] & 0xff) << 24));
  v.z = (int)(((unsigned)(q[8] & 0xff)) | ((unsigned)(q[9] & 0xff) << 8) | ((unsigned)(q[10] & 0xff) << 16) | ((unsigned)(q[11] & 0xff) << 24));
  v.w = (int)(((unsigned)(q[12] & 0xff)) | ((unsigned)(q[13] & 0xff) << 8) | ((unsigned)(q[14] & 0xff) << 16) | ((unsigned)(q[15] & 0xff) << 24));
  xq[p] = v;
}

// ---------------- K4/K6: int8 conv (stats pass / output pass) ----------------
// grid 1568 = 32 n * 7*7 tiles of 32x32 output pixels; 256 thr; 4 px x 16 cout per thread.
// cout processed in 2 chunks of 8 to keep live accumulators at 32 VGPRs (R1: a
// single acc[4][16] + unrolled taps spilled to scratch -> 290 MB phantom traffic).
template <bool WRITE_OUT>
__global__ __launch_bounds__(256, 4) void k_conv(const char* __restrict__ ws,
                                                 float* __restrict__ out,
                                                 float* __restrict__ partials) {
  const int4* __restrict__ xq = (const int4*)(ws + WS_XQ);
  const int4* __restrict__ wq4 = (const int4*)(ws + WS_WQ);
  __shared__ int4 sX[34 * 34];
  __shared__ int4 sW[144];
  __shared__ float sRedS[4][16];
  __shared__ float sRedQ[4][16];

  int tid = threadIdx.x;
  int b = blockIdx.x;
  int n = b / 49; int r = b - n * 49;
  int t_y = r / 7, t_x = r - t_y * 7;
  int h0 = t_y * 32, w0 = t_x * 32;

  if (tid < 144) sW[tid] = wq4[tid];
  for (int i = tid; i < 34 * 34; i += 256) {
    int row = i / 34, col = i - row * 34;
    int gh = h0 - 1 + row, gw = w0 - 1 + col;
    int4 v = {0, 0, 0, 0};
    if ((unsigned)gh < 224u && (unsigned)gw < 224u)
      v = xq[(n * 224 + gh) * 224 + gw];
    sX[i] = v;
  }
  __syncthreads();

  int tx = tid & 31, ty = tid >> 5;
  const float* hdr_f = (const float*)ws;

  for (int chunk = 0; chunk < 2; ++chunk) {
    int acc[4][8];
    #pragma unroll
    for (int p = 0; p < 4; ++p)
      #pragma unroll
      for (int c = 0; c < 8; ++c) acc[p][c] = 0;

    #pragma unroll
    for (int kh = 0; kh < 3; ++kh) {
      #pragma unroll
      for (int kw = 0; kw < 3; ++kw) {
        int4 xv[4];
        #pragma unroll
        for (int p = 0; p < 4; ++p) xv[p] = sX[(ty + 8 * p + kh) * 34 + tx + kw];
        #pragma unroll
        for (int c = 0; c < 8; ++c) {
          int4 wv = sW[(chunk * 8 + c) * 9 + kh * 3 + kw];
          #pragma unroll
          for (int p = 0; p < 4; ++p) {
            int a = acc[p][c];
            a = dot4(xv[p].x, wv.x, a);
            a = dot4(xv[p].y, wv.y, a);
            a = dot4(xv[p].z, wv.z, a);
            a = dot4(xv[p].w, wv.w, a);
            acc[p][c] = a;
          }
        }
      }
    }

    if (WRITE_OUT) {
      #pragma unroll
      for (int c = 0; c < 8; ++c) {
        int cc = chunk * 8 + c;
        float A = hdr_f[16 + cc], B = hdr_f[32 + cc];
        #pragma unroll
        for (int p = 0; p < 4; ++p) {
          float y = fmaf((float)acc[p][c], A, B);
          y = fminf(fmaxf(y, 0.0f), 6.0f);
          out[((n * 16 + cc) * 224 + (h0 + ty + 8 * p)) * 224 + (w0 + tx)] = y;
        }
      }
    } else {
      #pragma unroll
      for (int c = 0; c < 8; ++c) {
        int cc = chunk * 8 + c;
        int si = acc[0][c] + acc[1][c] + acc[2][c] + acc[3][c];  // exact in int32
        float ps = (float)si;
        float f0 = (float)acc[0][c], f1 = (float)acc[1][c];
        float f2 = (float)acc[2][c], f3 = (float)acc[3][c];
        float pq = f0 * f0 + f1 * f1 + f2 * f2 + f3 * f3;
        #pragma unroll
        for (int off = 32; off; off >>= 1) {
          ps += __shfl_down(ps, off, 64);
          pq += __shfl_down(pq, off, 64);
        }
        if ((tid & 63) == 0) { sRedS[tid >> 6][cc] = ps; sRedQ[tid >> 6][cc] = pq; }
      }
    }
  }

  if (!WRITE_OUT) {
    __syncthreads();
    if (tid < 32) {
      int c = tid & 15;
      float t;
      if (tid < 16) t = sRedS[0][c] + sRedS[1][c] + sRedS[2][c] + sRedS[3][c];
      else          t = sRedQ[0][c] + sRedQ[1][c] + sRedQ[2][c] + sRedQ[3][c];
      partials[b * 32 + tid] = t;
    }
  }
}

// ---------------- K5: finalize BN coefficients ----------------
__global__ void k_finalize(const float* __restrict__ partials,
                           const float* __restrict__ gamma,
                           const float* __restrict__ beta,
                           float* __restrict__ hdr_f) {
  __shared__ double sd[256];
  int tid = threadIdx.x;
  int v = tid & 31;
  int g = tid >> 5;  // 8 groups
  double acc = 0.0;
  for (int i = g; i < 1568; i += 8) acc += (double)partials[i * 32 + v];
  sd[tid] = acc;
  __syncthreads();
  if (tid < 32) {
    double t = 0.0;
    #pragma unroll
    for (int g2 = 0; g2 < 8; ++g2) t += sd[g2 * 32 + tid];
    sd[tid] = t;
  }
  __syncthreads();
  if (tid < 16) {
    double s = (double)hdr_f[2];
    const double M = (double)NPIX;
    double mean = s * sd[tid] / M;
    double ey2 = s * s * sd[16 + tid] / M;
    double var = ey2 - mean * mean;                 // biased var, matches jnp.var
    double inv = (double)gamma[tid] / sqrt(var + 1e-5);
    hdr_f[16 + tid] = (float)(s * inv);             // A: applied to raw int accumulator
    hdr_f[32 + tid] = (float)((double)beta[tid] - mean * inv);  // B
  }
}

extern "C" void kernel_launch(void* const* d_in, const int* in_sizes, int n_in,
                              void* d_out, int out_size, void* d_ws, size_t ws_size,
                              hipStream_t stream) {
  const float* x = (const float*)d_in[0];
  const float* w = (const float*)d_in[1];
  const float* gamma = (const float*)d_in[2];
  const float* beta = (const float*)d_in[3];
  float* out = (float*)d_out;
  char* ws = (char*)d_ws;

  hipMemsetAsync(ws, 0, 256, stream);  // zero header (absmax accumulator)
  k_absmax<<<2048, 256, 0, stream>>>(x, (unsigned*)ws);
  k_quant_w<<<1, 256, 0, stream>>>(w, ws);
  k_quant_x<<<6272, 256, 0, stream>>>(x, ws);
  k_conv<false><<<1568, 256, 0, stream>>>(ws, nullptr, (float*)(ws + WS_PART));
  k_finalize<<<1, 256, 0, stream>>>((const float*)(ws + WS_PART), gamma, beta, (float*)ws);
  k_conv<true><<<1568, 256, 0, stream>>>(ws, out, nullptr);
}

// Round 3
// 355.698 us; speedup vs baseline: 2.6109x; 2.6109x over previous
//
#include <hip/hip_runtime.h>
#include <stdint.h>

// Problem constants
#define QP 127.0f
#define HW2 50176            // 224*224
#define NPIX 1605632         // 32*224*224
#define NELEM 25690112       // 32*16*224*224

// ws layout (bytes)
#define WS_WQ   256          // 576 dwords packed weights
#define WS_PART 4096         // 1568*32 floats of per-block stat partials
#define WS_XQ   (1 << 20)    // NPIX * 16B of cin-packed int8 activations

__device__ __forceinline__ int dot4(int a, int b, int c) {
#if defined(__has_builtin) && __has_builtin(__builtin_amdgcn_sdot4)
  return __builtin_amdgcn_sdot4(a, b, c, false);
#else
  int r = c;
  r += (int)(signed char)(a)       * (int)(signed char)(b);
  r += (int)(signed char)(a >> 8)  * (int)(signed char)(b >> 8);
  r += (int)(signed char)(a >> 16) * (int)(signed char)(b >> 16);
  r += (a >> 24) * (b >> 24);
  return r;
#endif
}

// ---------------- K1: absmax(x) ----------------
__global__ void k_absmax(const float* __restrict__ x, unsigned* __restrict__ absmax_bits) {
  const float4* x4 = (const float4*)x;
  const int n4 = NELEM / 4;
  float m = 0.0f;
  for (int i = blockIdx.x * blockDim.x + threadIdx.x; i < n4; i += gridDim.x * blockDim.x) {
    float4 v = x4[i];
    m = fmaxf(m, fmaxf(fmaxf(fabsf(v.x), fabsf(v.y)), fmaxf(fabsf(v.z), fabsf(v.w))));
  }
  #pragma unroll
  for (int off = 32; off; off >>= 1) m = fmaxf(m, __shfl_down(m, off, 64));
  __shared__ float red[4];
  int lane = threadIdx.x & 63, wv = threadIdx.x >> 6;
  if (lane == 0) red[wv] = m;
  __syncthreads();
  if (threadIdx.x == 0) {
    m = fmaxf(fmaxf(red[0], red[1]), fmaxf(red[2], red[3]));
    atomicMax(absmax_bits, __float_as_uint(m));  // all values >= 0: uint order == float order
  }
}

// ---------------- K2: quantize weights, compute scales ----------------
__global__ void k_quant_w(const float* __restrict__ w, char* __restrict__ ws) {
  unsigned* hdr_u = (unsigned*)ws;
  float* hdr_f = (float*)ws;
  int* wq = (int*)(ws + WS_WQ);
  float m = 0.0f;
  for (int i = threadIdx.x; i < 2304; i += 256) m = fmaxf(m, fabsf(w[i]));
  #pragma unroll
  for (int off = 32; off; off >>= 1) m = fmaxf(m, __shfl_down(m, off, 64));
  __shared__ float red[4];
  __shared__ float s_sw;
  if ((threadIdx.x & 63) == 0) red[threadIdx.x >> 6] = m;
  __syncthreads();
  if (threadIdx.x == 0) {
    float mw = fmaxf(fmaxf(red[0], red[1]), fmaxf(red[2], red[3]));
    float sw = mw / QP;                              // matches ref: step = alpha/qp (f32 div)
    float sx = __uint_as_float(hdr_u[0]) / QP;
    hdr_f[1] = sw;
    hdr_f[2] = sx * sw;                              // combined dequant scale
    s_sw = sw;
  }
  __syncthreads();
  float sw = s_sw;
  // pack: wq[(cout*9 + kh*3+kw)*4 + c4], byte j of dword = cin 4*c4+j
  for (int i = threadIdx.x; i < 576; i += 256) {
    int cout = i / 36; int r = i - cout * 36;
    int tap = r >> 2;  int c4 = r & 3;
    int kh = tap / 3, kw = tap - kh * 3;
    unsigned bits = 0;
    #pragma unroll
    for (int j = 0; j < 4; ++j) {
      int cin = c4 * 4 + j;
      float v = w[((cout * 16 + cin) * 3 + kh) * 3 + kw];
      int q = (int)rintf(v / sw);                    // rint = round-half-even = jnp.round
      q = max(-127, min(127, q));
      bits |= ((unsigned)(q & 0xff)) << (8 * j);
    }
    wq[i] = (int)bits;
  }
}

// ---------------- K3: quantize x -> NHWC cin-packed int8 ----------------
__global__ void k_quant_x(const float* __restrict__ x, char* __restrict__ ws) {
  const unsigned* hdr_u = (const unsigned*)ws;
  int4* xq = (int4*)(ws + WS_XQ);
  float sx = __uint_as_float(hdr_u[0]) / QP;
  int p = blockIdx.x * 256 + threadIdx.x;            // 6272*256 == NPIX exactly
  int n = p / HW2;
  int hw = p - n * HW2;
  const float* xb = x + (size_t)n * 16 * HW2 + hw;   // coalesced per-channel reads
  int q[16];
  #pragma unroll
  for (int c = 0; c < 16; ++c) {
    float t = xb[c * HW2] / sx;                      // f32 div, matches ref
    int qq = (int)rintf(t);
    q[c] = max(-127, min(127, qq));
  }
  int4 v;
  v.x = (int)(((unsigned)(q[0] & 0xff)) | ((unsigned)(q[1] & 0xff) << 8) | ((unsigned)(q[2] & 0xff) << 16) | ((unsigned)(q[3] & 0xff) << 24));
  v.y = (int)(((unsigned)(q[4] & 0xff)) | ((unsigned)(q[5] & 0xff) << 8) | ((unsigned)(q[6] & 0xff) << 16) | ((unsigned)(q[7] & 0xff) << 24));
  v.z = (int)(((unsigned)(q[8] & 0xff)) | ((unsigned)(q[9] & 0xff) << 8) | ((unsigned)(q[10] & 0xff) << 16) | ((unsigned)(q[11] & 0xff) << 24));
  v.w = (int)(((unsigned)(q[12] & 0xff)) | ((unsigned)(q[13] & 0xff) << 8) | ((unsigned)(q[14] & 0xff) << 16) | ((unsigned)(q[15] & 0xff) << 24));
  xq[p] = v;
}

// ---------------- K4/K6: int8 conv (stats pass / output pass) ----------------
// grid 1568 = 32 n * 7*7 tiles of 32x32 output pixels; 256 thr; 4 px x 16 cout per thread.
// R1 lesson: fully-unrolled 3x3 taps let the scheduler hoist all 36 ds_read_b128
// (144 VGPRs of xv) ahead of the dot chain -> spill at 256 VGPRs. R2 lesson: capping
// VGPRs to 64 spills worse. Fix: keep acc[4][16] but force tap loop NOT unrolled so
// only one tap's loads are live (~95 regs total); no occupancy cap.
template <bool WRITE_OUT>
__global__ __launch_bounds__(256) void k_conv(const char* __restrict__ ws,
                                              float* __restrict__ out,
                                              float* __restrict__ partials) {
  const int4* __restrict__ xq = (const int4*)(ws + WS_XQ);
  const int4* __restrict__ wq4 = (const int4*)(ws + WS_WQ);
  __shared__ int4 sX[34 * 34];
  __shared__ int4 sW[144];
  __shared__ float sRedS[4][16];
  __shared__ float sRedQ[4][16];

  int tid = threadIdx.x;
  int b = blockIdx.x;
  int n = b / 49; int r = b - n * 49;
  int t_y = r / 7, t_x = r - t_y * 7;
  int h0 = t_y * 32, w0 = t_x * 32;

  if (tid < 144) sW[tid] = wq4[tid];
  for (int i = tid; i < 34 * 34; i += 256) {
    int row = i / 34, col = i - row * 34;
    int gh = h0 - 1 + row, gw = w0 - 1 + col;
    int4 v = {0, 0, 0, 0};
    if ((unsigned)gh < 224u && (unsigned)gw < 224u)
      v = xq[(n * 224 + gh) * 224 + gw];
    sX[i] = v;
  }
  __syncthreads();

  int tx = tid & 31, ty = tid >> 5;

  int acc[4][16];
  #pragma unroll
  for (int p = 0; p < 4; ++p)
    #pragma unroll
    for (int c = 0; c < 16; ++c) acc[p][c] = 0;

  #pragma unroll 1
  for (int tap = 0; tap < 9; ++tap) {
    int kh = tap / 3, kw = tap - kh * 3;
    int4 xv[4];
    #pragma unroll
    for (int p = 0; p < 4; ++p) xv[p] = sX[(ty + 8 * p + kh) * 34 + tx + kw];
    #pragma unroll
    for (int c = 0; c < 16; ++c) {
      int4 wv = sW[c * 9 + tap];
      #pragma unroll
      for (int p = 0; p < 4; ++p) {
        int a = acc[p][c];
        a = dot4(xv[p].x, wv.x, a);
        a = dot4(xv[p].y, wv.y, a);
        a = dot4(xv[p].z, wv.z, a);
        a = dot4(xv[p].w, wv.w, a);
        acc[p][c] = a;
      }
    }
  }

  if (WRITE_OUT) {
    const float* hdr_f = (const float*)ws;
    #pragma unroll
    for (int c = 0; c < 16; ++c) {
      float A = hdr_f[16 + c], B = hdr_f[32 + c];
      #pragma unroll
      for (int p = 0; p < 4; ++p) {
        float y = fmaf((float)acc[p][c], A, B);
        y = fminf(fmaxf(y, 0.0f), 6.0f);
        out[((n * 16 + c) * 224 + (h0 + ty + 8 * p)) * 224 + (w0 + tx)] = y;
      }
    }
  } else {
    #pragma unroll
    for (int c = 0; c < 16; ++c) {
      int si = acc[0][c] + acc[1][c] + acc[2][c] + acc[3][c];  // exact in int32
      float ps = (float)si;
      float f0 = (float)acc[0][c], f1 = (float)acc[1][c];
      float f2 = (float)acc[2][c], f3 = (float)acc[3][c];
      float pq = f0 * f0 + f1 * f1 + f2 * f2 + f3 * f3;
      #pragma unroll
      for (int off = 32; off; off >>= 1) {
        ps += __shfl_down(ps, off, 64);
        pq += __shfl_down(pq, off, 64);
      }
      if ((tid & 63) == 0) { sRedS[tid >> 6][c] = ps; sRedQ[tid >> 6][c] = pq; }
    }
    __syncthreads();
    if (tid < 32) {
      int c = tid & 15;
      float t;
      if (tid < 16) t = sRedS[0][c] + sRedS[1][c] + sRedS[2][c] + sRedS[3][c];
      else          t = sRedQ[0][c] + sRedQ[1][c] + sRedQ[2][c] + sRedQ[3][c];
      partials[b * 32 + tid] = t;
    }
  }
}

// ---------------- K5: finalize BN coefficients ----------------
__global__ void k_finalize(const float* __restrict__ partials,
                           const float* __restrict__ gamma,
                           const float* __restrict__ beta,
                           float* __restrict__ hdr_f) {
  __shared__ double sd[256];
  int tid = threadIdx.x;
  int v = tid & 31;
  int g = tid >> 5;  // 8 groups
  double acc = 0.0;
  for (int i = g; i < 1568; i += 8) acc += (double)partials[i * 32 + v];
  sd[tid] = acc;
  __syncthreads();
  if (tid < 32) {
    double t = 0.0;
    #pragma unroll
    for (int g2 = 0; g2 < 8; ++g2) t += sd[g2 * 32 + tid];
    sd[tid] = t;
  }
  __syncthreads();
  if (tid < 16) {
    double s = (double)hdr_f[2];
    const double M = (double)NPIX;
    double mean = s * sd[tid] / M;
    double ey2 = s * s * sd[16 + tid] / M;
    double var = ey2 - mean * mean;                 // biased var, matches jnp.var
    double inv = (double)gamma[tid] / sqrt(var + 1e-5);
    hdr_f[16 + tid] = (float)(s * inv);             // A: applied to raw int accumulator
    hdr_f[32 + tid] = (float)((double)beta[tid] - mean * inv);  // B
  }
}

extern "C" void kernel_launch(void* const* d_in, const int* in_sizes, int n_in,
                              void* d_out, int out_size, void* d_ws, size_t ws_size,
                              hipStream_t stream) {
  const float* x = (const float*)d_in[0];
  const float* w = (const float*)d_in[1];
  const float* gamma = (const float*)d_in[2];
  const float* beta = (const float*)d_in[3];
  float* out = (float*)d_out;
  char* ws = (char*)d_ws;

  hipMemsetAsync(ws, 0, 256, stream);  // zero header (absmax accumulator)
  k_absmax<<<2048, 256, 0, stream>>>(x, (unsigned*)ws);
  k_quant_w<<<1, 256, 0, stream>>>(w, ws);
  k_quant_x<<<6272, 256, 0, stream>>>(x, ws);
  k_conv<false><<<1568, 256, 0, stream>>>(ws, nullptr, (float*)(ws + WS_PART));
  k_finalize<<<1, 256, 0, stream>>>((const float*)(ws + WS_PART), gamma, beta, (float*)ws);
  k_conv<true><<<1568, 256, 0, stream>>>(ws, out, nullptr);
}

// Round 4
// 349.326 us; speedup vs baseline: 2.6586x; 1.0182x over previous
//
#include <hip/hip_runtime.h>
#include <stdint.h>

// Problem constants
#define QP 127.0f
#define HW2 50176            // 224*224
#define NPIX 1605632         // 32*224*224
#define NELEM 25690112       // 32*16*224*224

// ws layout (bytes)
#define WS_WQ   256          // 576 dwords packed weights
#define WS_PART 4096         // 1568*32 floats of per-block stat partials
#define WS_XQ   (1 << 20)    // NPIX * 16B of cin-packed int8 activations

__device__ __forceinline__ int dot4(int a, int b, int c) {
#if defined(__has_builtin) && __has_builtin(__builtin_amdgcn_sdot4)
  return __builtin_amdgcn_sdot4(a, b, c, false);
#else
  int r = c;
  r += (int)(signed char)(a)       * (int)(signed char)(b);
  r += (int)(signed char)(a >> 8)  * (int)(signed char)(b >> 8);
  r += (int)(signed char)(a >> 16) * (int)(signed char)(b >> 16);
  r += (a >> 24) * (b >> 24);
  return r;
#endif
}

// ---------------- K1: absmax(x) ----------------
__global__ void k_absmax(const float* __restrict__ x, unsigned* __restrict__ absmax_bits) {
  const float4* x4 = (const float4*)x;
  const int n4 = NELEM / 4;
  float m = 0.0f;
  for (int i = blockIdx.x * blockDim.x + threadIdx.x; i < n4; i += gridDim.x * blockDim.x) {
    float4 v = x4[i];
    m = fmaxf(m, fmaxf(fmaxf(fabsf(v.x), fabsf(v.y)), fmaxf(fabsf(v.z), fabsf(v.w))));
  }
  #pragma unroll
  for (int off = 32; off; off >>= 1) m = fmaxf(m, __shfl_down(m, off, 64));
  __shared__ float red[4];
  int lane = threadIdx.x & 63, wv = threadIdx.x >> 6;
  if (lane == 0) red[wv] = m;
  __syncthreads();
  if (threadIdx.x == 0) {
    m = fmaxf(fmaxf(red[0], red[1]), fmaxf(red[2], red[3]));
    atomicMax(absmax_bits, __float_as_uint(m));  // all values >= 0: uint order == float order
  }
}

// ---------------- K2: quantize weights, compute scales ----------------
__global__ void k_quant_w(const float* __restrict__ w, char* __restrict__ ws) {
  unsigned* hdr_u = (unsigned*)ws;
  float* hdr_f = (float*)ws;
  int* wq = (int*)(ws + WS_WQ);
  float m = 0.0f;
  for (int i = threadIdx.x; i < 2304; i += 256) m = fmaxf(m, fabsf(w[i]));
  #pragma unroll
  for (int off = 32; off; off >>= 1) m = fmaxf(m, __shfl_down(m, off, 64));
  __shared__ float red[4];
  __shared__ float s_sw;
  if ((threadIdx.x & 63) == 0) red[threadIdx.x >> 6] = m;
  __syncthreads();
  if (threadIdx.x == 0) {
    float mw = fmaxf(fmaxf(red[0], red[1]), fmaxf(red[2], red[3]));
    float sw = mw / QP;                              // matches ref: step = alpha/qp (f32 div)
    float sx = __uint_as_float(hdr_u[0]) / QP;
    hdr_f[1] = sw;
    hdr_f[2] = sx * sw;                              // combined dequant scale
    s_sw = sw;
  }
  __syncthreads();
  float sw = s_sw;
  // pack: wq[(cout*9 + kh*3+kw)*4 + c4], byte j of dword = cin 4*c4+j
  for (int i = threadIdx.x; i < 576; i += 256) {
    int cout = i / 36; int r = i - cout * 36;
    int tap = r >> 2;  int c4 = r & 3;
    int kh = tap / 3, kw = tap - kh * 3;
    unsigned bits = 0;
    #pragma unroll
    for (int j = 0; j < 4; ++j) {
      int cin = c4 * 4 + j;
      float v = w[((cout * 16 + cin) * 3 + kh) * 3 + kw];
      int q = (int)rintf(v / sw);                    // rint = round-half-even = jnp.round
      q = max(-127, min(127, q));
      bits |= ((unsigned)(q & 0xff)) << (8 * j);
    }
    wq[i] = (int)bits;
  }
}

// ---------------- K3: quantize x -> NHWC cin-packed int8 ----------------
// 4 consecutive pixels per thread: float4 loads per channel (4x fewer load
// instructions than R3's scalar loads), 4 contiguous int4 stores.
__global__ void k_quant_x(const float* __restrict__ x, char* __restrict__ ws) {
  const unsigned* hdr_u = (const unsigned*)ws;
  int4* xq = (int4*)(ws + WS_XQ);
  float sx = __uint_as_float(hdr_u[0]) / QP;
  int t = blockIdx.x * 256 + threadIdx.x;            // grid 1568*256 = NPIX/4
  int p0 = t * 4;
  int n = p0 / HW2;                                  // HW2 % 4 == 0: no n-crossing
  int hw = p0 - n * HW2;
  const float4* xb = (const float4*)(x + (size_t)n * 16 * HW2 + hw);
  unsigned comp[4][4];
  #pragma unroll
  for (int j = 0; j < 4; ++j)
    #pragma unroll
    for (int k = 0; k < 4; ++k) comp[j][k] = 0u;
  #pragma unroll
  for (int c = 0; c < 16; ++c) {
    float4 vc = xb[c * (HW2 / 4)];
    float f[4] = {vc.x, vc.y, vc.z, vc.w};
    #pragma unroll
    for (int j = 0; j < 4; ++j) {
      int q = (int)rintf(f[j] / sx);                 // f32 div, matches ref
      q = max(-127, min(127, q));
      comp[j][c >> 2] |= ((unsigned)(q & 0xff)) << (8 * (c & 3));
    }
  }
  #pragma unroll
  for (int j = 0; j < 4; ++j) {
    int4 v;
    v.x = (int)comp[j][0]; v.y = (int)comp[j][1];
    v.z = (int)comp[j][2]; v.w = (int)comp[j][3];
    xq[p0 + j] = v;
  }
}

// ---------------- K4/K6: int8 conv (stats pass / output pass) ----------------
// grid 1568 = 32 n * 7*7 tiles of 32x32 output pixels; 256 thr; 4 px x 16 cout/thread.
// Weights come from GLOBAL memory with block-uniform indices -> compiler emits
// s_load into SGPRs (v_dot4 takes one SGPR operand). This removes the 16
// broadcast ds_read_b128 per tap that made R3's conv LDS-pipe-bound (per-CU LDS
// demand ~2100 cyc/tap vs 1540 VALU cyc/tap at 12 waves).
// Tap loop kept #pragma unroll 1: full unroll hoists 36 ds_reads -> spill (R1).
template <bool WRITE_OUT>
__global__ __launch_bounds__(256) void k_conv(const char* __restrict__ ws,
                                              float* __restrict__ out,
                                              float* __restrict__ partials) {
  const int4* __restrict__ xq = (const int4*)(ws + WS_XQ);
  const int4* __restrict__ wq4 = (const int4*)(ws + WS_WQ);
  __shared__ int4 sX[34 * 34];
  __shared__ float sRedS[4][16];
  __shared__ float sRedQ[4][16];

  int tid = threadIdx.x;
  int b = blockIdx.x;
  int n = b / 49; int r = b - n * 49;
  int t_y = r / 7, t_x = r - t_y * 7;
  int h0 = t_y * 32, w0 = t_x * 32;

  for (int i = tid; i < 34 * 34; i += 256) {
    int row = i / 34, col = i - row * 34;
    int gh = h0 - 1 + row, gw = w0 - 1 + col;
    int4 v = {0, 0, 0, 0};
    if ((unsigned)gh < 224u && (unsigned)gw < 224u)
      v = xq[(n * 224 + gh) * 224 + gw];
    sX[i] = v;
  }
  __syncthreads();

  int tx = tid & 31, ty = tid >> 5;

  int acc[4][16];
  #pragma unroll
  for (int p = 0; p < 4; ++p)
    #pragma unroll
    for (int c = 0; c < 16; ++c) acc[p][c] = 0;

  #pragma unroll 1
  for (int tap = 0; tap < 9; ++tap) {
    int kh = tap / 3, kw = tap - kh * 3;             // uniform -> scalar ops
    int4 xv[4];
    #pragma unroll
    for (int p = 0; p < 4; ++p) xv[p] = sX[(ty + 8 * p + kh) * 34 + tx + kw];
    #pragma unroll
    for (int c = 0; c < 16; ++c) {
      int4 wv = wq4[c * 9 + tap];                    // uniform index -> s_load
      #pragma unroll
      for (int p = 0; p < 4; ++p) {
        int a = acc[p][c];
        a = dot4(xv[p].x, wv.x, a);
        a = dot4(xv[p].y, wv.y, a);
        a = dot4(xv[p].z, wv.z, a);
        a = dot4(xv[p].w, wv.w, a);
        acc[p][c] = a;
      }
    }
  }

  if (WRITE_OUT) {
    const float* hdr_f = (const float*)ws;
    #pragma unroll
    for (int c = 0; c < 16; ++c) {
      float A = hdr_f[16 + c], B = hdr_f[32 + c];
      #pragma unroll
      for (int p = 0; p < 4; ++p) {
        float y = fmaf((float)acc[p][c], A, B);
        y = fminf(fmaxf(y, 0.0f), 6.0f);
        out[((n * 16 + c) * 224 + (h0 + ty + 8 * p)) * 224 + (w0 + tx)] = y;
      }
    }
  } else {
    #pragma unroll
    for (int c = 0; c < 16; ++c) {
      int si = acc[0][c] + acc[1][c] + acc[2][c] + acc[3][c];  // exact in int32
      float ps = (float)si;
      float f0 = (float)acc[0][c], f1 = (float)acc[1][c];
      float f2 = (float)acc[2][c], f3 = (float)acc[3][c];
      float pq = f0 * f0 + f1 * f1 + f2 * f2 + f3 * f3;
      #pragma unroll
      for (int off = 32; off; off >>= 1) {
        ps += __shfl_down(ps, off, 64);
        pq += __shfl_down(pq, off, 64);
      }
      if ((tid & 63) == 0) { sRedS[tid >> 6][c] = ps; sRedQ[tid >> 6][c] = pq; }
    }
    __syncthreads();
    if (tid < 32) {
      int c = tid & 15;
      float t;
      if (tid < 16) t = sRedS[0][c] + sRedS[1][c] + sRedS[2][c] + sRedS[3][c];
      else          t = sRedQ[0][c] + sRedQ[1][c] + sRedQ[2][c] + sRedQ[3][c];
      partials[b * 32 + tid] = t;
    }
  }
}

// ---------------- K5: finalize BN coefficients ----------------
__global__ void k_finalize(const float* __restrict__ partials,
                           const float* __restrict__ gamma,
                           const float* __restrict__ beta,
                           float* __restrict__ hdr_f) {
  __shared__ double sd[256];
  int tid = threadIdx.x;
  int v = tid & 31;
  int g = tid >> 5;  // 8 groups
  double acc = 0.0;
  for (int i = g; i < 1568; i += 8) acc += (double)partials[i * 32 + v];
  sd[tid] = acc;
  __syncthreads();
  if (tid < 32) {
    double t = 0.0;
    #pragma unroll
    for (int g2 = 0; g2 < 8; ++g2) t += sd[g2 * 32 + tid];
    sd[tid] = t;
  }
  __syncthreads();
  if (tid < 16) {
    double s = (double)hdr_f[2];
    const double M = (double)NPIX;
    double mean = s * sd[tid] / M;
    double ey2 = s * s * sd[16 + tid] / M;
    double var = ey2 - mean * mean;                 // biased var, matches jnp.var
    double inv = (double)gamma[tid] / sqrt(var + 1e-5);
    hdr_f[16 + tid] = (float)(s * inv);             // A: applied to raw int accumulator
    hdr_f[32 + tid] = (float)((double)beta[tid] - mean * inv);  // B
  }
}

extern "C" void kernel_launch(void* const* d_in, const int* in_sizes, int n_in,
                              void* d_out, int out_size, void* d_ws, size_t ws_size,
                              hipStream_t stream) {
  const float* x = (const float*)d_in[0];
  const float* w = (const float*)d_in[1];
  const float* gamma = (const float*)d_in[2];
  const float* beta = (const float*)d_in[3];
  float* out = (float*)d_out;
  char* ws = (char*)d_ws;

  hipMemsetAsync(ws, 0, 256, stream);  // zero header (absmax accumulator)
  k_absmax<<<2048, 256, 0, stream>>>(x, (unsigned*)ws);
  k_quant_w<<<1, 256, 0, stream>>>(w, ws);
  k_quant_x<<<1568, 256, 0, stream>>>(x, ws);
  k_conv<false><<<1568, 256, 0, stream>>>(ws, nullptr, (float*)(ws + WS_PART));
  k_finalize<<<1, 256, 0, stream>>>((const float*)(ws + WS_PART), gamma, beta, (float*)ws);
  k_conv<true><<<1568, 256, 0, stream>>>(ws, out, nullptr);
}

// Round 5
// 297.913 us; speedup vs baseline: 3.1174x; 1.1726x over previous
//
#include <hip/hip_runtime.h>
#include <stdint.h>

// Problem constants
#define QP 127.0f
#define HW2 50176            // 224*224
#define NPIX 1605632         // 32*224*224
#define NELEM 25690112       // 32*16*224*224

// ws layout (bytes)
#define WS_WQ   256          // 576 dwords packed weights
#define WS_PART 4096         // 1568*32 floats of per-block stat partials
#define WS_XQ   (1 << 20)    // NPIX * 16B of cin-packed int8 activations

__device__ __forceinline__ int dot4(int a, int b, int c) {
#if defined(__has_builtin) && __has_builtin(__builtin_amdgcn_sdot4)
  return __builtin_amdgcn_sdot4(a, b, c, false);
#else
  int r = c;
  r += (int)(signed char)(a)       * (int)(signed char)(b);
  r += (int)(signed char)(a >> 8)  * (int)(signed char)(b >> 8);
  r += (int)(signed char)(a >> 16) * (int)(signed char)(b >> 16);
  r += (a >> 24) * (b >> 24);
  return r;
#endif
}

// ---------------- K0: quantize weights; also zero absmax slot ----------------
// Runs FIRST (needs nothing from absmax); thread 0 zeroes hdr_u[0] so the
// separate 256-B memset dispatch is gone. Combined scale moved to k_finalize.
__global__ void k_quant_w(const float* __restrict__ w, char* __restrict__ ws) {
  unsigned* hdr_u = (unsigned*)ws;
  float* hdr_f = (float*)ws;
  int* wq = (int*)(ws + WS_WQ);
  if (threadIdx.x == 0) hdr_u[0] = 0u;               // absmax accumulator
  float m = 0.0f;
  for (int i = threadIdx.x; i < 2304; i += 256) m = fmaxf(m, fabsf(w[i]));
  #pragma unroll
  for (int off = 32; off; off >>= 1) m = fmaxf(m, __shfl_down(m, off, 64));
  __shared__ float red[4];
  __shared__ float s_sw;
  if ((threadIdx.x & 63) == 0) red[threadIdx.x >> 6] = m;
  __syncthreads();
  if (threadIdx.x == 0) {
    float mw = fmaxf(fmaxf(red[0], red[1]), fmaxf(red[2], red[3]));
    float sw = mw / QP;                              // matches ref: step = alpha/qp (f32 div)
    hdr_f[1] = sw;
    s_sw = sw;
  }
  __syncthreads();
  float sw = s_sw;
  // pack: wq[(cout*9 + kh*3+kw)*4 + c4], byte j of dword = cin 4*c4+j
  for (int i = threadIdx.x; i < 576; i += 256) {
    int cout = i / 36; int r = i - cout * 36;
    int tap = r >> 2;  int c4 = r & 3;
    int kh = tap / 3, kw = tap - kh * 3;
    unsigned bits = 0;
    #pragma unroll
    for (int j = 0; j < 4; ++j) {
      int cin = c4 * 4 + j;
      float v = w[((cout * 16 + cin) * 3 + kh) * 3 + kw];
      int q = (int)rintf(v / sw);                    // rint = round-half-even = jnp.round
      q = max(-127, min(127, q));
      bits |= ((unsigned)(q & 0xff)) << (8 * j);
    }
    wq[i] = (int)bits;
  }
}

// ---------------- K1: absmax(x) ----------------
__global__ void k_absmax(const float* __restrict__ x, unsigned* __restrict__ absmax_bits) {
  const float4* x4 = (const float4*)x;
  const int n4 = NELEM / 4;
  float m = 0.0f;
  for (int i = blockIdx.x * blockDim.x + threadIdx.x; i < n4; i += gridDim.x * blockDim.x) {
    float4 v = x4[i];
    m = fmaxf(m, fmaxf(fmaxf(fabsf(v.x), fabsf(v.y)), fmaxf(fabsf(v.z), fabsf(v.w))));
  }
  #pragma unroll
  for (int off = 32; off; off >>= 1) m = fmaxf(m, __shfl_down(m, off, 64));
  __shared__ float red[4];
  int lane = threadIdx.x & 63, wv = threadIdx.x >> 6;
  if (lane == 0) red[wv] = m;
  __syncthreads();
  if (threadIdx.x == 0) {
    m = fmaxf(fmaxf(red[0], red[1]), fmaxf(red[2], red[3]));
    atomicMax(absmax_bits, __float_as_uint(m));  // all values >= 0: uint order == float order
  }
}

// ---------------- K2: quantize x -> NHWC cin-packed int8 ----------------
// 4 consecutive pixels per thread: float4 loads per channel, 4 int4 stores.
__global__ void k_quant_x(const float* __restrict__ x, char* __restrict__ ws) {
  const unsigned* hdr_u = (const unsigned*)ws;
  int4* xq = (int4*)(ws + WS_XQ);
  float sx = __uint_as_float(hdr_u[0]) / QP;
  int t = blockIdx.x * 256 + threadIdx.x;            // grid 1568*256 = NPIX/4
  int p0 = t * 4;
  int n = p0 / HW2;                                  // HW2 % 4 == 0: no n-crossing
  int hw = p0 - n * HW2;
  const float4* xb = (const float4*)(x + (size_t)n * 16 * HW2 + hw);
  unsigned comp[4][4];
  #pragma unroll
  for (int j = 0; j < 4; ++j)
    #pragma unroll
    for (int k = 0; k < 4; ++k) comp[j][k] = 0u;
  #pragma unroll
  for (int c = 0; c < 16; ++c) {
    float4 vc = xb[c * (HW2 / 4)];
    float f[4] = {vc.x, vc.y, vc.z, vc.w};
    #pragma unroll
    for (int j = 0; j < 4; ++j) {
      int q = (int)rintf(f[j] / sx);                 // f32 div, matches ref
      q = max(-127, min(127, q));
      comp[j][c >> 2] |= ((unsigned)(q & 0xff)) << (8 * (c & 3));
    }
  }
  #pragma unroll
  for (int j = 0; j < 4; ++j) {
    int4 v;
    v.x = (int)comp[j][0]; v.y = (int)comp[j][1];
    v.z = (int)comp[j][2]; v.w = (int)comp[j][3];
    xq[p0 + j] = v;
  }
}

// ---------------- K3/K5: int8 conv (stats pass / output pass) ----------------
// grid 1568 = 32 n * 7*7 tiles of 32x32 px; 256 thr; 4 CONSECUTIVE rows x 16 cout
// per thread. Consecutive rows share tap inputs: 6 row-reads per kw column (18
// ds_read_b128 total vs 36 with strided rows). Weights via uniform-index global
// loads -> s_load into SGPRs. kw loop NOT unrolled (full unroll -> spill, R1).
// Stats reduction: LDS transpose (stride 257, conflict-free) + 2 shuffles,
// replacing R4's 192 ds_bpermute/wave that made the stats pass LDS-pipe-bound.
template <bool WRITE_OUT>
__global__ __launch_bounds__(256) void k_conv(const char* __restrict__ ws,
                                              float* __restrict__ out,
                                              float* __restrict__ partials) {
  const int4* __restrict__ xq = (const int4*)(ws + WS_XQ);
  const int4* __restrict__ wq4 = (const int4*)(ws + WS_WQ);
  __shared__ int4 sX[34 * 34];                       // 18496 B; aliased as f32 in epilogue
  __shared__ float sRedS[4][16];
  __shared__ float sRedQ[4][16];

  int tid = threadIdx.x;
  int b = blockIdx.x;
  int n = b / 49; int r = b - n * 49;
  int t_y = r / 7, t_x = r - t_y * 7;
  int h0 = t_y * 32, w0 = t_x * 32;

  for (int i = tid; i < 34 * 34; i += 256) {
    int row = i / 34, col = i - row * 34;
    int gh = h0 - 1 + row, gw = w0 - 1 + col;
    int4 v = {0, 0, 0, 0};
    if ((unsigned)gh < 224u && (unsigned)gw < 224u)
      v = xq[(n * 224 + gh) * 224 + gw];
    sX[i] = v;
  }
  __syncthreads();

  int tx = tid & 31, ty = tid >> 5;                  // rows ty*4 .. ty*4+3

  int acc[4][16];
  #pragma unroll
  for (int p = 0; p < 4; ++p)
    #pragma unroll
    for (int c = 0; c < 16; ++c) acc[p][c] = 0;

  #pragma unroll 1
  for (int kw = 0; kw < 3; ++kw) {
    int4 xr[6];                                      // sX rows ty*4 .. ty*4+5
    #pragma unroll
    for (int j = 0; j < 6; ++j) xr[j] = sX[(ty * 4 + j) * 34 + tx + kw];
    #pragma unroll
    for (int c = 0; c < 16; ++c) {
      #pragma unroll
      for (int kh = 0; kh < 3; ++kh) {
        int4 wv = wq4[(c * 3 + kh) * 3 + kw];        // uniform -> s_load_dwordx4
        #pragma unroll
        for (int p = 0; p < 4; ++p) {
          int4 xv = xr[p + kh];
          int a = acc[p][c];
          a = dot4(xv.x, wv.x, a);
          a = dot4(xv.y, wv.y, a);
          a = dot4(xv.z, wv.z, a);
          a = dot4(xv.w, wv.w, a);
          acc[p][c] = a;
        }
      }
    }
  }

  if (WRITE_OUT) {
    const float* hdr_f = (const float*)ws;
    #pragma unroll
    for (int c = 0; c < 16; ++c) {
      float A = hdr_f[16 + c], B = hdr_f[32 + c];
      #pragma unroll
      for (int p = 0; p < 4; ++p) {
        float y = fmaf((float)acc[p][c], A, B);
        y = fminf(fmaxf(y, 0.0f), 6.0f);
        out[((n * 16 + c) * 224 + (h0 + ty * 4 + p)) * 224 + (w0 + tx)] = y;
      }
    }
  } else {
    float* sR = (float*)sX;                          // reuse staging LDS (16448 B used)
    int wv_ = tid >> 6, seg = tid >> 4, cc = tid & 15;
    float totS, totQ;
    // ---- round 1: si ----
    __syncthreads();                                 // all sX reads done
    #pragma unroll
    for (int c = 0; c < 16; ++c) {
      int si = acc[0][c] + acc[1][c] + acc[2][c] + acc[3][c];  // exact in int32
      sR[c * 257 + tid] = (float)si;
    }
    __syncthreads();
    {
      float ps = 0.0f;
      #pragma unroll
      for (int j = 0; j < 16; ++j) ps += sR[cc * 257 + (seg & 3) * 16 + j + (tid >> 6) * 0];
      // seg within wave: lanes l: seg_local = (l >> 4); global seg = wv_*4 + seg_local
      ps += __shfl_xor(ps, 16, 64);
      ps += __shfl_xor(ps, 32, 64);
      if ((tid & 63) < 16) sRedS[wv_][cc] = ps;
      totS = ps;  (void)totS;
    }
    __syncthreads();                                 // sR readers done before reuse
    // ---- round 2: sum of squares ----
    #pragma unroll
    for (int c = 0; c < 16; ++c) {
      float f0 = (float)acc[0][c], f1 = (float)acc[1][c];
      float f2 = (float)acc[2][c], f3 = (float)acc[3][c];
      sR[c * 257 + tid] = f0 * f0 + f1 * f1 + f2 * f2 + f3 * f3;
    }
    __syncthreads();
    {
      float pq = 0.0f;
      #pragma unroll
      for (int j = 0; j < 16; ++j) pq += sR[cc * 257 + (seg & 3) * 16 + j];
      pq += __shfl_xor(pq, 16, 64);
      pq += __shfl_xor(pq, 32, 64);
      if ((tid & 63) < 16) sRedQ[wv_][cc] = pq;
      totQ = pq;  (void)totQ;
    }
    __syncthreads();
    if (tid < 32) {
      int c = tid & 15;
      float t;
      if (tid < 16) t = sRedS[0][c] + sRedS[1][c] + sRedS[2][c] + sRedS[3][c];
      else          t = sRedQ[0][c] + sRedQ[1][c] + sRedQ[2][c] + sRedQ[3][c];
      partials[b * 32 + tid] = t;
    }
  }
}

// ---------------- K4: finalize BN coefficients (parallel reduction) ----------------
// 256 threads, float4 grid-stride over the 50176 partials (49 independent loads
// per thread -> latency hidden), double accumulate, LDS tree. R4's version was a
// single block doing ~196 dependent loads (latency-bound, ~20 us).
__global__ void k_finalize(const float* __restrict__ partials,
                           const float* __restrict__ gamma,
                           const float* __restrict__ beta,
                           float* __restrict__ hdr_f) {
  const unsigned* hdr_u = (const unsigned*)hdr_f;
  __shared__ double sdd[256][4];
  __shared__ double sfin[32];
  int t = threadIdx.x;
  const float4* p4 = (const float4*)partials;        // 12544 float4s
  double d0 = 0, d1 = 0, d2 = 0, d3 = 0;
  #pragma unroll 7
  for (int k = 0; k < 49; ++k) {
    float4 v = p4[t + 256 * k];
    d0 += (double)v.x; d1 += (double)v.y; d2 += (double)v.z; d3 += (double)v.w;
  }
  // stat id of d_j is ((4*t) % 32) + j  (1024 == 0 mod 32 -> constant over k)
  sdd[t][0] = d0; sdd[t][1] = d1; sdd[t][2] = d2; sdd[t][3] = d3;
  __syncthreads();
  if (t < 32) {
    // stat t gathers from threads t' = (t>>2) + 8*i, component j = t&3
    double s = 0.0;
    #pragma unroll 8
    for (int i = 0; i < 32; ++i) s += sdd[(t >> 2) + 8 * i][t & 3];
    sfin[t] = s;
  }
  __syncthreads();
  if (t < 16) {
    float sxf = __uint_as_float(hdr_u[0]) / QP;
    float sf = sxf * hdr_f[1];                       // combined dequant scale (f32, as before)
    double s = (double)sf;
    const double M = (double)NPIX;
    double mean = s * sfin[t] / M;
    double ey2 = s * s * sfin[16 + t] / M;
    double var = ey2 - mean * mean;                  // biased var, matches jnp.var
    double inv = (double)gamma[t] / sqrt(var + 1e-5);
    hdr_f[16 + t] = (float)(s * inv);                // A: applied to raw int accumulator
    hdr_f[32 + t] = (float)((double)beta[t] - mean * inv);  // B
  }
}

extern "C" void kernel_launch(void* const* d_in, const int* in_sizes, int n_in,
                              void* d_out, int out_size, void* d_ws, size_t ws_size,
                              hipStream_t stream) {
  const float* x = (const float*)d_in[0];
  const float* w = (const float*)d_in[1];
  const float* gamma = (const float*)d_in[2];
  const float* beta = (const float*)d_in[3];
  float* out = (float*)d_out;
  char* ws = (char*)d_ws;

  k_quant_w<<<1, 256, 0, stream>>>(w, ws);           // also zeroes absmax slot
  k_absmax<<<2048, 256, 0, stream>>>(x, (unsigned*)ws);
  k_quant_x<<<1568, 256, 0, stream>>>(x, ws);
  k_conv<false><<<1568, 256, 0, stream>>>(ws, nullptr, (float*)(ws + WS_PART));
  k_finalize<<<1, 256, 0, stream>>>((const float*)(ws + WS_PART), gamma, beta, (float*)ws);
  k_conv<true><<<1568, 256, 0, stream>>>(ws, out, nullptr);
}